// Round 5
// baseline (2973.243 us; speedup 1.0000x reference)
//
#include <hip/hip_runtime.h>

using u16 = unsigned short;

__device__ __forceinline__ float bf2f(u16 u) {
  return __uint_as_float(((unsigned int)u) << 16);
}
__device__ __forceinline__ u16 f2bf(float f) {
  unsigned int u = __float_as_uint(f);
  unsigned int r = u + 0x7FFFu + ((u >> 16) & 1u);
  return (u16)(r >> 16);
}

// ---------------- K0: transpose pam_v_w [c][ci] -> wvT [ci][c] ---------------
__global__ void k_prep_wv(const float* __restrict__ wv, float* __restrict__ wvT) {
  int idx = blockIdx.x * 256 + threadIdx.x;   // 16384
  int ci = idx >> 7, c = idx & 127;
  wvT[ci * 128 + c] = wv[c * 128 + ci];
}

// ---------------- K1: BN+ReLU for both branches, f32 out ---------------------
__global__ void k_bnrelu2(const float* __restrict__ x,
    const float* __restrict__ wa, const float* __restrict__ ba,
    const float* __restrict__ ma, const float* __restrict__ va,
    const float* __restrict__ wc, const float* __restrict__ bc,
    const float* __restrict__ mc, const float* __restrict__ vc,
    float* __restrict__ xa, float* __restrict__ xcb) {
  int i4 = (blockIdx.x * 256 + threadIdx.x) * 4;   // over 2*512*4096
  int c = (i4 >> 12) & 511;
  float sA = wa[c] * rsqrtf(va[c] + 1e-5f);
  float bA = ba[c] - ma[c] * sA;
  float sC = wc[c] * rsqrtf(vc[c] + 1e-5f);
  float bC = bc[c] - mc[c] * sC;
  float4 xv = *(const float4*)(x + i4);
  float4 oa, oc;
  oa.x = fmaxf(xv.x * sA + bA, 0.f); oc.x = fmaxf(xv.x * sC + bC, 0.f);
  oa.y = fmaxf(xv.y * sA + bA, 0.f); oc.y = fmaxf(xv.y * sC + bC, 0.f);
  oa.z = fmaxf(xv.z * sA + bA, 0.f); oc.z = fmaxf(xv.z * sC + bC, 0.f);
  oa.w = fmaxf(xv.w * sA + bA, 0.f); oc.w = fmaxf(xv.w * sC + bC, 0.f);
  *(float4*)(xa + i4) = oa;
  *(float4*)(xcb + i4) = oc;
}

// ---------------- K2: 3x3 conv SAME, 512->128, f32 in/out, simple ------------
__global__ __launch_bounds__(256) void k_conv3(const float* __restrict__ xin,
    const float* __restrict__ wconv, float* __restrict__ out) {
  __shared__ float wlds[4608];
  int t = threadIdx.x;
  int co = blockIdx.y, b = blockIdx.z;
  for (int idx = t; idx < 4608; idx += 256)
    wlds[idx] = wconv[co * 4608 + idx];
  __syncthreads();
  int hw = blockIdx.x * 256 + t;
  int h = hw >> 6, w = hw & 63;
  bool wm = (w > 0), wp = (w < 63);
  float acc = 0.f;
  const float* xb = xin + ((size_t)b * 512 << 12);
  for (int ci = 0; ci < 512; ++ci) {
    const float* ip = xb + ((size_t)ci << 12);
    const float* wq = wlds + ci * 9;
#pragma unroll
    for (int kh = 0; kh < 3; ++kh) {
      int hh = h + kh - 1;
      if (hh < 0 || hh > 63) continue;
      const float* base = ip + (hh << 6) + w;
      float xm = wm ? base[-1] : 0.f;
      float x0 = base[0];
      float xp = wp ? base[1] : 0.f;
      acc = fmaf(wq[kh * 3 + 0], xm,
            fmaf(wq[kh * 3 + 1], x0,
            fmaf(wq[kh * 3 + 2], xp, acc)));
    }
  }
  out[((size_t)(b * 128 + co) << 12) + hw] = acc;
}

// ---------------- K3a: 1x1 conv -> q,k ([b][16][4096] f32) -------------------
__global__ void k_qk(const float* __restrict__ sa0,
    const float* __restrict__ wq, const float* __restrict__ bq,
    const float* __restrict__ wk, const float* __restrict__ bk,
    float* __restrict__ qb, float* __restrict__ kb) {
  int n = blockIdx.x * 256 + threadIdx.x;
  int co = blockIdx.y, b = blockIdx.z;
  const float* w; float* dst; float bias;
  if (co < 16) { w = wq + co * 128; bias = bq[co]; dst = qb + ((b * 16 + co) << 12); }
  else { int c2 = co - 16; w = wk + c2 * 128; bias = bk[c2]; dst = kb + ((b * 16 + c2) << 12); }
  const float* s = sa0 + ((size_t)b * 128 << 12) + n;
  float acc = bias;
  for (int ci = 0; ci < 128; ++ci) acc = fmaf(w[ci], s[ci << 12], acc);
  dst[n] = acc;
}

// ---------------- K3b: 1x1 conv -> v, stored transposed vt[b][n][c] ----------
__global__ void k_vt(const float* __restrict__ sa0, const float* __restrict__ wvT,
                     const float* __restrict__ bv, float* __restrict__ vt) {
  int t = threadIdx.x;
  int c = t & 127, nh = t >> 7;
  int n = blockIdx.x * 2 + nh, b = blockIdx.y;
  const float* s = sa0 + ((size_t)b * 128 << 12) + n;
  float acc = bv[c];
  for (int ci = 0; ci < 128; ++ci) acc = fmaf(wvT[ci * 128 + c], s[ci << 12], acc);
  vt[((size_t)(b * 4096 + n)) * 128 + c] = acc;
}

// ---------------- K4: PAM softmax row stats (max, 1/sum) ---------------------
__global__ __launch_bounds__(256) void k_pam_stats(const float* __restrict__ qb,
    const float* __restrict__ kb, float* __restrict__ rmax, float* __restrict__ rinv) {
  int t = threadIdx.x, lane = t & 63, wid = t >> 6;
  int b = blockIdx.y;
  int n = blockIdx.x * 4 + wid;
  float qreg[16];
  const float* qp = qb + ((size_t)b * 16 << 12) + n;
#pragma unroll
  for (int ch = 0; ch < 16; ++ch) qreg[ch] = qp[ch << 12];
  const float* kp = kb + ((size_t)b * 16 << 12);
  float mx = -1e30f, se = 0.f;
  for (int m = lane; m < 4096; m += 64) {
    float e = 0.f;
#pragma unroll
    for (int ch = 0; ch < 16; ++ch) e = fmaf(qreg[ch], kp[(ch << 12) + m], e);
    float nm = fmaxf(mx, e);
    se = se * __expf(mx - nm) + __expf(e - nm);
    mx = nm;
  }
#pragma unroll
  for (int off = 32; off >= 1; off >>= 1) {
    float om = __shfl_xor(mx, off);
    float os = __shfl_xor(se, off);
    float nm = fmaxf(mx, om);
    se = se * __expf(mx - nm) + os * __expf(om - nm);
    mx = nm;
  }
  if (lane == 0) { rmax[(b << 12) + n] = mx; rinv[(b << 12) + n] = 1.f / se; }
}

// ---------------- K5: PAM PV, one block per output position n ----------------
__global__ __launch_bounds__(256) void k_pam_pv(const float* __restrict__ qb,
    const float* __restrict__ kb, const float* __restrict__ vt,
    const float* __restrict__ rmax, const float* __restrict__ rinv,
    const float* __restrict__ sa0, const float* __restrict__ gamma,
    float* __restrict__ sa1) {
  __shared__ float pL[4096];
  __shared__ float qn[16];
  int t = threadIdx.x;
  int n = blockIdx.x, b = blockIdx.y;
  if (t < 16) qn[t] = qb[((b * 16 + t) << 12) + n];
  __syncthreads();
  float mx = rmax[(b << 12) + n];
  float rv = rinv[(b << 12) + n];
  const float* kpb = kb + ((size_t)b * 16 << 12);
  for (int m = t; m < 4096; m += 256) {
    float e = 0.f;
#pragma unroll
    for (int ch = 0; ch < 16; ++ch) e = fmaf(qn[ch], kpb[(ch << 12) + m], e);
    pL[m] = __expf(fminf(e - mx, 0.f)) * rv;
  }
  __syncthreads();
  if (t < 128) {
    int c = t;
    const float* vp = vt + ((size_t)b * 4096) * 128 + c;
    float acc = 0.f;
    for (int m = 0; m < 4096; ++m) acc = fmaf(pL[m], vp[m * 128], acc);
    size_t o = ((size_t)(b * 128 + c) << 12) + n;
    sa1[o] = fmaf(gamma[0], acc, sa0[o]);
  }
}

// ---------------- K6a: CAM Gram energy, block per row c, deterministic -------
__global__ __launch_bounds__(256) void k_cam_energy(const float* __restrict__ f,
                                                    float* __restrict__ energy) {
  __shared__ float fc[4096];
  int t = threadIdx.x;
  int c = blockIdx.x, b = blockIdx.y;
  const float* fr = f + ((size_t)(b * 128 + c) << 12);
  for (int i = t; i < 4096; i += 256) fc[i] = fr[i];
  __syncthreads();
  if (t < 128) {
    int d = t;
    const float* fd = f + ((size_t)(b * 128 + d) << 12);
    float acc = 0.f;
    for (int nn = 0; nn < 4096; ++nn) acc = fmaf(fc[nn], fd[nn], acc);
    energy[((b * 128 + c) << 7) + d] = acc;
  }
}

// ---------------- K6b: CAM softmax row (attn = softmax(rowmax - e)) ----------
__global__ void k_cam_softmax(const float* __restrict__ energy, float* __restrict__ attn) {
  int lane = threadIdx.x;   // 64
  int c = blockIdx.x, b = blockIdx.y;
  const float* e = energy + ((b * 128 + c) << 7);
  float e0 = e[lane], e1 = e[lane + 64];
  float mn = fminf(e0, e1);
#pragma unroll
  for (int off = 32; off >= 1; off >>= 1) mn = fminf(mn, __shfl_xor(mn, off));
  float p0 = __expf(fminf(mn - e0, 0.f)), p1 = __expf(fminf(mn - e1, 0.f));
  float s = p0 + p1;
#pragma unroll
  for (int off = 32; off >= 1; off >>= 1) s += __shfl_xor(s, off);
  float inv = 1.f / s;
  float* a = attn + ((b * 128 + c) << 7);
  a[lane] = p0 * inv;
  a[lane + 64] = p1 * inv;
}

// ---------------- K7: CAM out + residual -------------------------------------
__global__ __launch_bounds__(256) void k_cam_out(const float* __restrict__ f,
    const float* __restrict__ attn, const float* __restrict__ gamma,
    float* __restrict__ sc1) {
  __shared__ float at2[128 * 16];
  int t = threadIdx.x;
  int b = blockIdx.z, c0 = blockIdx.y * 16;
  int n = blockIdx.x * 256 + t;
  for (int idx = t; idx < 2048; idx += 256) {
    int d = idx >> 4, cc = idx & 15;
    at2[idx] = attn[((b * 128 + c0 + cc) << 7) + d];
  }
  __syncthreads();
  float acc[16] = {};
  const float* fb = f + ((size_t)b * 128 << 12) + n;
  for (int d = 0; d < 128; ++d) {
    float fv = fb[d << 12];
    const float* ap = at2 + d * 16;
#pragma unroll
    for (int cc = 0; cc < 16; ++cc) acc[cc] = fmaf(ap[cc], fv, acc[cc]);
  }
  float g = gamma[0];
#pragma unroll
  for (int cc = 0; cc < 16; ++cc) {
    size_t o = ((size_t)(b * 128 + c0 + cc) << 12) + n;
    sc1[o] = fmaf(g, acc[cc], f[o]);
  }
}

// ---------------- K8: BN+ReLU + 1x1 conv 128->512, simple --------------------
__global__ __launch_bounds__(256) void k_branch_out(
    const float* __restrict__ sa1, const float* __restrict__ sc1,
    const float* __restrict__ wa_, const float* __restrict__ ba_,
    const float* __restrict__ ma_, const float* __restrict__ va_,
    const float* __restrict__ wc_, const float* __restrict__ bc_,
    const float* __restrict__ mc_, const float* __restrict__ vc_,
    const float* __restrict__ Wa, const float* __restrict__ Ba,
    const float* __restrict__ Wc, const float* __restrict__ Bc,
    u16* __restrict__ sa2, u16* __restrict__ sc2) {
  int z = blockIdx.z;
  int b = z & 1, br = z >> 1;
  const float* src = br ? sc1 : sa1;
  const float* bw = br ? wc_ : wa_;
  const float* bb = br ? bc_ : ba_;
  const float* bm = br ? mc_ : ma_;
  const float* bvv = br ? vc_ : va_;
  const float* W = br ? Wc : Wa;
  const float* Bs = br ? Bc : Ba;
  u16* dst = br ? sc2 : sa2;
  __shared__ float scl[128], shf[128];
  int t = threadIdx.x;
  int co = blockIdx.y;
  int n = blockIdx.x * 256 + t;
  if (t < 128) {
    float s = bw[t] * rsqrtf(bvv[t] + 1e-5f);
    scl[t] = s;
    shf[t] = bb[t] - bm[t] * s;
  }
  __syncthreads();
  const float* sp = src + ((size_t)b * 128 << 12) + n;
  const float* wrow = W + co * 128;
  float acc = Bs[co];
  for (int ci = 0; ci < 128; ++ci) {
    float xv = fmaxf(fmaf(sp[ci << 12], scl[ci], shf[ci]), 0.f);
    acc = fmaf(wrow[ci], xv, acc);
  }
  dst[((size_t)(b * 512 + co) << 12) + n] = f2bf(acc);
}

// ---------------- K9: fusion + all three class heads, f32 outputs ------------
__global__ __launch_bounds__(256) void k_heads(const u16* __restrict__ sa2,
    const u16* __restrict__ sc2,
    const float* __restrict__ wf, const float* __restrict__ wa, const float* __restrict__ wc,
    const float* __restrict__ bfb, const float* __restrict__ bab, const float* __restrict__ bcb,
    float* __restrict__ outFusion, float* __restrict__ outCls) {
  int t = threadIdx.x;
  int b = blockIdx.y;
  int n = blockIdx.x * 256 + t;
  float af[5] = {}, aa[5] = {}, ac[5] = {};
  for (int c = 0; c < 512; ++c) {
    size_t o = ((size_t)(b * 512 + c) << 12) + n;
    float a = bf2f(sa2[o]), cc = bf2f(sc2[o]);
    float s = a + cc;
    outFusion[o] = s;
#pragma unroll
    for (int cls = 0; cls < 5; ++cls) {
      af[cls] = fmaf(wf[cls * 512 + c], s, af[cls]);
      aa[cls] = fmaf(wa[cls * 512 + c], a, aa[cls]);
      ac[cls] = fmaf(wc[cls * 512 + c], cc, ac[cls]);
    }
  }
#pragma unroll
  for (int cls = 0; cls < 5; ++cls) {
    int o = ((b * 5 + cls) << 12) + n;
    outCls[o] = af[cls] + bfb[cls];
    outCls[40960 + o] = aa[cls] + bab[cls];
    outCls[81920 + o] = ac[cls] + bcb[cls];
  }
}

extern "C" void kernel_launch(void* const* d_in, const int* in_sizes, int n_in,
                              void* d_out, int out_size, void* d_ws, size_t ws_size,
                              hipStream_t stream) {
  (void)in_sizes; (void)n_in; (void)out_size; (void)ws_size;
  const float* x      = (const float*)d_in[0];
  const float* bnaw   = (const float*)d_in[1];
  const float* bnab   = (const float*)d_in[2];
  const float* bnam   = (const float*)d_in[3];
  const float* bnav   = (const float*)d_in[4];
  const float* convaw = (const float*)d_in[5];
  const float* bncw   = (const float*)d_in[6];
  const float* bncb   = (const float*)d_in[7];
  const float* bncm   = (const float*)d_in[8];
  const float* bncv   = (const float*)d_in[9];
  const float* convcw = (const float*)d_in[10];
  const float* pqw    = (const float*)d_in[11];
  const float* pqb    = (const float*)d_in[12];
  const float* pkw    = (const float*)d_in[13];
  const float* pkb    = (const float*)d_in[14];
  const float* pvw    = (const float*)d_in[15];
  const float* pvb    = (const float*)d_in[16];
  const float* pgam   = (const float*)d_in[17];
  const float* cgam   = (const float*)d_in[18];
  const float* bna1w  = (const float*)d_in[19];
  const float* bna1b  = (const float*)d_in[20];
  const float* bna1m  = (const float*)d_in[21];
  const float* bna1v  = (const float*)d_in[22];
  const float* conva1w = (const float*)d_in[23];
  const float* conva1b = (const float*)d_in[24];
  const float* bnc1w  = (const float*)d_in[25];
  const float* bnc1b  = (const float*)d_in[26];
  const float* bnc1m  = (const float*)d_in[27];
  const float* bnc1v  = (const float*)d_in[28];
  const float* convc1w = (const float*)d_in[29];
  const float* convc1b = (const float*)d_in[30];
  const float* outaw  = (const float*)d_in[31];
  const float* outab  = (const float*)d_in[32];
  const float* outcw  = (const float*)d_in[33];
  const float* outcb  = (const float*)d_in[34];
  const float* outfw  = (const float*)d_in[35];
  const float* outfb  = (const float*)d_in[36];

  char* wsb = (char*)d_ws;
  size_t off = 0;
  auto take = [&](size_t bytes) -> void* {
    void* p = wsb + off;
    off += (bytes + 255) & ~(size_t)255;
    return p;
  };
  float* wvT   = (float*)take((size_t)128 * 128 * 4);
  float* xa    = (float*)take((size_t)2 * 512 * 4096 * 4);
  float* xcb   = (float*)take((size_t)2 * 512 * 4096 * 4);
  float* sa0   = (float*)take((size_t)2 * 128 * 4096 * 4);
  float* sc0   = (float*)take((size_t)2 * 128 * 4096 * 4);
  float* qb    = (float*)take((size_t)2 * 16 * 4096 * 4);
  float* kbuf  = (float*)take((size_t)2 * 16 * 4096 * 4);
  float* vt    = (float*)take((size_t)2 * 4096 * 128 * 4);
  float* rmax  = (float*)take((size_t)2 * 4096 * 4);
  float* rinv  = (float*)take((size_t)2 * 4096 * 4);
  float* sa1   = (float*)take((size_t)2 * 128 * 4096 * 4);
  float* sc1   = (float*)take((size_t)2 * 128 * 4096 * 4);
  float* energy = (float*)take((size_t)2 * 128 * 128 * 4);
  float* attn  = (float*)take((size_t)2 * 128 * 128 * 4);
  u16*   sa2   = (u16*)take((size_t)2 * 512 * 4096 * 2);
  u16*   sc2   = (u16*)take((size_t)2 * 512 * 4096 * 2);

  float* outF = (float*)d_out;                        // f32 outputs!
  float* outCls = outF + (size_t)2 * 512 * 4096;

  k_prep_wv<<<64, 256, 0, stream>>>(pvw, wvT);
  k_bnrelu2<<<4096, 256, 0, stream>>>(x, bnaw, bnab, bnam, bnav,
                                      bncw, bncb, bncm, bncv, xa, xcb);
  k_conv3<<<dim3(16, 128, 2), 256, 0, stream>>>(xa, convaw, sa0);
  k_conv3<<<dim3(16, 128, 2), 256, 0, stream>>>(xcb, convcw, sc0);
  k_qk<<<dim3(16, 32, 2), 256, 0, stream>>>(sa0, pqw, pqb, pkw, pkb, qb, kbuf);
  k_vt<<<dim3(2048, 2), 256, 0, stream>>>(sa0, wvT, pvb, vt);
  k_pam_stats<<<dim3(1024, 2), 256, 0, stream>>>(qb, kbuf, rmax, rinv);
  k_pam_pv<<<dim3(4096, 2), 256, 0, stream>>>(qb, kbuf, vt, rmax, rinv, sa0, pgam, sa1);
  k_cam_energy<<<dim3(128, 2), 256, 0, stream>>>(sc0, energy);
  k_cam_softmax<<<dim3(128, 2), 64, 0, stream>>>(energy, attn);
  k_cam_out<<<dim3(16, 8, 2), 256, 0, stream>>>(sc0, attn, cgam, sc1);
  k_branch_out<<<dim3(16, 512, 4), 256, 0, stream>>>(sa1, sc1,
      bna1w, bna1b, bna1m, bna1v, bnc1w, bnc1b, bnc1m, bnc1v,
      conva1w, conva1b, convc1w, convc1b, sa2, sc2);
  k_heads<<<dim3(16, 2), 256, 0, stream>>>(sa2, sc2, outfw, outaw, outcw,
                                           outfb, outab, outcb, outF, outCls);
}

// Round 6
// 2122.253 us; speedup vs baseline: 1.4010x; 1.4010x over previous
//
#include <hip/hip_runtime.h>

using u16 = unsigned short;

__device__ __forceinline__ float bf2f(u16 u) {
  return __uint_as_float(((unsigned int)u) << 16);
}
__device__ __forceinline__ u16 f2bf(float f) {
  unsigned int u = __float_as_uint(f);
  unsigned int r = u + 0x7FFFu + ((u >> 16) & 1u);
  return (u16)(r >> 16);
}

// ---------------- K0: transpose pam_v_w [c][ci] -> wvT [ci][c] ---------------
__global__ void k_prep_wv(const float* __restrict__ wv, float* __restrict__ wvT) {
  int idx = blockIdx.x * 256 + threadIdx.x;   // 16384
  int ci = idx >> 7, c = idx & 127;
  wvT[ci * 128 + c] = wv[c * 128 + ci];
}

// ---------------- K1: BN+ReLU for both branches, f32 out ---------------------
__global__ void k_bnrelu2(const float* __restrict__ x,
    const float* __restrict__ wa, const float* __restrict__ ba,
    const float* __restrict__ ma, const float* __restrict__ va,
    const float* __restrict__ wc, const float* __restrict__ bc,
    const float* __restrict__ mc, const float* __restrict__ vc,
    float* __restrict__ xa, float* __restrict__ xcb) {
  int i4 = (blockIdx.x * 256 + threadIdx.x) * 4;   // over 2*512*4096
  int c = (i4 >> 12) & 511;
  float sA = wa[c] * rsqrtf(va[c] + 1e-5f);
  float bA = ba[c] - ma[c] * sA;
  float sC = wc[c] * rsqrtf(vc[c] + 1e-5f);
  float bC = bc[c] - mc[c] * sC;
  float4 xv = *(const float4*)(x + i4);
  float4 oa, oc;
  oa.x = fmaxf(xv.x * sA + bA, 0.f); oc.x = fmaxf(xv.x * sC + bC, 0.f);
  oa.y = fmaxf(xv.y * sA + bA, 0.f); oc.y = fmaxf(xv.y * sC + bC, 0.f);
  oa.z = fmaxf(xv.z * sA + bA, 0.f); oc.z = fmaxf(xv.z * sC + bC, 0.f);
  oa.w = fmaxf(xv.w * sA + bA, 0.f); oc.w = fmaxf(xv.w * sC + bC, 0.f);
  *(float4*)(xa + i4) = oa;
  *(float4*)(xcb + i4) = oc;
}

// ---------------- K2: 3x3 conv SAME 512->128, co-tiled + LDS input staging ---
// block: 256 thr = 4 rows x 64 cols; computes 16 co for that tile.
// grid: (16 h-groups, 8 co-groups, 4 = b*2(?) no: z = b + 2*branch)
__global__ __launch_bounds__(256) void k_conv3t(
    const float* __restrict__ xa, const float* __restrict__ xcb,
    const float* __restrict__ wa, const float* __restrict__ wc,
    float* __restrict__ sa0, float* __restrict__ sc0) {
  __shared__ float ls[16 * 396];   // 16 ci x 6 rows x 66 (w-halo), zero-padded
  int t = threadIdx.x;
  int hg = blockIdx.x, cg = blockIdx.y, z = blockIdx.z;
  int b = z & 1, br = z >> 1;
  const float* xin = br ? xcb : xa;
  const float* wconv = br ? wc : wa;
  float* out = br ? sc0 : sa0;
  int h0 = hg * 4;
  int w = t & 63, hl = t >> 6;
  int co0 = cg * 16;
  float acc[16] = {};
  const float* xb = xin + ((size_t)b * 512 << 12);
  for (int ci0 = 0; ci0 < 512; ci0 += 16) {
    __syncthreads();
    for (int idx = t; idx < 6336; idx += 256) {
      int ci_l = idx / 396;
      int rem = idx - ci_l * 396;
      int row = rem / 66;          // 0..5 -> gh = h0-1+row
      int w66 = rem - row * 66;    // 0..65 -> gw = w66-1
      int gh = h0 - 1 + row;
      int gw = w66 - 1;
      float v = 0.f;
      if (gh >= 0 && gh < 64 && gw >= 0 && gw < 64)
        v = xb[((size_t)(ci0 + ci_l) << 12) + (gh << 6) + gw];
      ls[idx] = v;
    }
    __syncthreads();
    for (int ci_l = 0; ci_l < 16; ++ci_l) {
      const float* c = ls + ci_l * 396 + (hl + 1) * 66 + (w + 1);
      float x00 = c[-67], x01 = c[-66], x02 = c[-65];
      float x10 = c[-1],  x11 = c[0],   x12 = c[1];
      float x20 = c[65],  x21 = c[66],  x22 = c[67];
      const float* wp = wconv + (size_t)co0 * 4608 + (ci0 + ci_l) * 9;
#pragma unroll
      for (int co = 0; co < 16; ++co) {
        const float* wq = wp + co * 4608;   // wave-uniform -> scalar loads
        acc[co] = fmaf(wq[0], x00, fmaf(wq[1], x01, fmaf(wq[2], x02,
                  fmaf(wq[3], x10, fmaf(wq[4], x11, fmaf(wq[5], x12,
                  fmaf(wq[6], x20, fmaf(wq[7], x21, fmaf(wq[8], x22, acc[co])))))))));
      }
    }
  }
  int hw = ((h0 + hl) << 6) + w;
#pragma unroll
  for (int co = 0; co < 16; ++co)
    out[((size_t)(b * 128 + co0 + co) << 12) + hw] = acc[co];
}

// ---------------- K3a: 1x1 conv -> q,k ([b][16][4096] f32) -------------------
__global__ void k_qk(const float* __restrict__ sa0,
    const float* __restrict__ wq, const float* __restrict__ bq,
    const float* __restrict__ wk, const float* __restrict__ bk,
    float* __restrict__ qb, float* __restrict__ kb) {
  int n = blockIdx.x * 256 + threadIdx.x;
  int co = blockIdx.y, b = blockIdx.z;
  const float* w; float* dst; float bias;
  if (co < 16) { w = wq + co * 128; bias = bq[co]; dst = qb + ((b * 16 + co) << 12); }
  else { int c2 = co - 16; w = wk + c2 * 128; bias = bk[c2]; dst = kb + ((b * 16 + c2) << 12); }
  const float* s = sa0 + ((size_t)b * 128 << 12) + n;
  float acc = bias;
  for (int ci = 0; ci < 128; ++ci) acc = fmaf(w[ci], s[ci << 12], acc);
  dst[n] = acc;
}

// ---------------- K3b: 1x1 conv -> v, stored transposed vt[b][n][c] ----------
__global__ void k_vt(const float* __restrict__ sa0, const float* __restrict__ wvT,
                     const float* __restrict__ bv, float* __restrict__ vt) {
  int t = threadIdx.x;
  int c = t & 127, nh = t >> 7;
  int n = blockIdx.x * 2 + nh, b = blockIdx.y;
  const float* s = sa0 + ((size_t)b * 128 << 12) + n;
  float acc = bv[c];
  for (int ci = 0; ci < 128; ++ci) acc = fmaf(wvT[ci * 128 + c], s[ci << 12], acc);
  vt[((size_t)(b * 4096 + n)) * 128 + c] = acc;
}

// ---------------- K4: PAM softmax row stats (max, 1/sum) ---------------------
__global__ __launch_bounds__(256) void k_pam_stats(const float* __restrict__ qb,
    const float* __restrict__ kb, float* __restrict__ rmax, float* __restrict__ rinv) {
  int t = threadIdx.x, lane = t & 63, wid = t >> 6;
  int b = blockIdx.y;
  int n = blockIdx.x * 4 + wid;
  float qreg[16];
  const float* qp = qb + ((size_t)b * 16 << 12) + n;
#pragma unroll
  for (int ch = 0; ch < 16; ++ch) qreg[ch] = qp[ch << 12];
  const float* kp = kb + ((size_t)b * 16 << 12);
  float mx = -1e30f, se = 0.f;
  for (int m = lane; m < 4096; m += 64) {
    float e = 0.f;
#pragma unroll
    for (int ch = 0; ch < 16; ++ch) e = fmaf(qreg[ch], kp[(ch << 12) + m], e);
    float nm = fmaxf(mx, e);
    se = se * __expf(mx - nm) + __expf(e - nm);
    mx = nm;
  }
#pragma unroll
  for (int off = 32; off >= 1; off >>= 1) {
    float om = __shfl_xor(mx, off);
    float os = __shfl_xor(se, off);
    float nm = fmaxf(mx, om);
    se = se * __expf(mx - nm) + os * __expf(om - nm);
    mx = nm;
  }
  if (lane == 0) { rmax[(b << 12) + n] = mx; rinv[(b << 12) + n] = 1.f / se; }
}

// ---------------- K5: PAM PV, one block per output position n ----------------
__global__ __launch_bounds__(256) void k_pam_pv(const float* __restrict__ qb,
    const float* __restrict__ kb, const float* __restrict__ vt,
    const float* __restrict__ rmax, const float* __restrict__ rinv,
    const float* __restrict__ sa0, const float* __restrict__ gamma,
    float* __restrict__ sa1) {
  __shared__ float pL[4096];
  __shared__ float qn[16];
  int t = threadIdx.x;
  int n = blockIdx.x, b = blockIdx.y;
  if (t < 16) qn[t] = qb[((b * 16 + t) << 12) + n];
  __syncthreads();
  float mx = rmax[(b << 12) + n];
  float rv = rinv[(b << 12) + n];
  const float* kpb = kb + ((size_t)b * 16 << 12);
  for (int m = t; m < 4096; m += 256) {
    float e = 0.f;
#pragma unroll
    for (int ch = 0; ch < 16; ++ch) e = fmaf(qn[ch], kpb[(ch << 12) + m], e);
    pL[m] = __expf(fminf(e - mx, 0.f)) * rv;
  }
  __syncthreads();
  if (t < 128) {
    int c = t;
    const float* vp = vt + ((size_t)b * 4096) * 128 + c;
    float acc = 0.f;
    for (int m = 0; m < 4096; ++m) acc = fmaf(pL[m], vp[m * 128], acc);
    size_t o = ((size_t)(b * 128 + c) << 12) + n;
    sa1[o] = fmaf(gamma[0], acc, sa0[o]);
  }
}

// ---------------- K6a: CAM Gram energy, block per row c, deterministic -------
__global__ __launch_bounds__(256) void k_cam_energy(const float* __restrict__ f,
                                                    float* __restrict__ energy) {
  __shared__ float fc[4096];
  int t = threadIdx.x;
  int c = blockIdx.x, b = blockIdx.y;
  const float* fr = f + ((size_t)(b * 128 + c) << 12);
  for (int i = t; i < 4096; i += 256) fc[i] = fr[i];
  __syncthreads();
  if (t < 128) {
    int d = t;
    const float* fd = f + ((size_t)(b * 128 + d) << 12);
    float acc = 0.f;
    for (int nn = 0; nn < 4096; ++nn) acc = fmaf(fc[nn], fd[nn], acc);
    energy[((b * 128 + c) << 7) + d] = acc;
  }
}

// ---------------- K6b: CAM softmax row (attn = softmax(rowmax - e)) ----------
__global__ void k_cam_softmax(const float* __restrict__ energy, float* __restrict__ attn) {
  int lane = threadIdx.x;   // 64
  int c = blockIdx.x, b = blockIdx.y;
  const float* e = energy + ((b * 128 + c) << 7);
  float e0 = e[lane], e1 = e[lane + 64];
  float mn = fminf(e0, e1);
#pragma unroll
  for (int off = 32; off >= 1; off >>= 1) mn = fminf(mn, __shfl_xor(mn, off));
  float p0 = __expf(fminf(mn - e0, 0.f)), p1 = __expf(fminf(mn - e1, 0.f));
  float s = p0 + p1;
#pragma unroll
  for (int off = 32; off >= 1; off >>= 1) s += __shfl_xor(s, off);
  float inv = 1.f / s;
  float* a = attn + ((b * 128 + c) << 7);
  a[lane] = p0 * inv;
  a[lane + 64] = p1 * inv;
}

// ---------------- K7: CAM out + residual -------------------------------------
__global__ __launch_bounds__(256) void k_cam_out(const float* __restrict__ f,
    const float* __restrict__ attn, const float* __restrict__ gamma,
    float* __restrict__ sc1) {
  __shared__ float at2[128 * 16];
  int t = threadIdx.x;
  int b = blockIdx.z, c0 = blockIdx.y * 16;
  int n = blockIdx.x * 256 + t;
  for (int idx = t; idx < 2048; idx += 256) {
    int d = idx >> 4, cc = idx & 15;
    at2[idx] = attn[((b * 128 + c0 + cc) << 7) + d];
  }
  __syncthreads();
  float acc[16] = {};
  const float* fb = f + ((size_t)b * 128 << 12) + n;
  for (int d = 0; d < 128; ++d) {
    float fv = fb[d << 12];
    const float* ap = at2 + d * 16;
#pragma unroll
    for (int cc = 0; cc < 16; ++cc) acc[cc] = fmaf(ap[cc], fv, acc[cc]);
  }
  float g = gamma[0];
#pragma unroll
  for (int cc = 0; cc < 16; ++cc) {
    size_t o = ((size_t)(b * 128 + c0 + cc) << 12) + n;
    sc1[o] = fmaf(g, acc[cc], f[o]);
  }
}

// ---------------- K8: BN+ReLU + 1x1 conv 128->512, simple --------------------
__global__ __launch_bounds__(256) void k_branch_out(
    const float* __restrict__ sa1, const float* __restrict__ sc1,
    const float* __restrict__ wa_, const float* __restrict__ ba_,
    const float* __restrict__ ma_, const float* __restrict__ va_,
    const float* __restrict__ wc_, const float* __restrict__ bc_,
    const float* __restrict__ mc_, const float* __restrict__ vc_,
    const float* __restrict__ Wa, const float* __restrict__ Ba,
    const float* __restrict__ Wc, const float* __restrict__ Bc,
    u16* __restrict__ sa2, u16* __restrict__ sc2) {
  int z = blockIdx.z;
  int b = z & 1, br = z >> 1;
  const float* src = br ? sc1 : sa1;
  const float* bw = br ? wc_ : wa_;
  const float* bb = br ? bc_ : ba_;
  const float* bm = br ? mc_ : ma_;
  const float* bvv = br ? vc_ : va_;
  const float* W = br ? Wc : Wa;
  const float* Bs = br ? Bc : Ba;
  u16* dst = br ? sc2 : sa2;
  __shared__ float scl[128], shf[128];
  int t = threadIdx.x;
  int co = blockIdx.y;
  int n = blockIdx.x * 256 + t;
  if (t < 128) {
    float s = bw[t] * rsqrtf(bvv[t] + 1e-5f);
    scl[t] = s;
    shf[t] = bb[t] - bm[t] * s;
  }
  __syncthreads();
  const float* sp = src + ((size_t)b * 128 << 12) + n;
  const float* wrow = W + co * 128;
  float acc = Bs[co];
  for (int ci = 0; ci < 128; ++ci) {
    float xv = fmaxf(fmaf(sp[ci << 12], scl[ci], shf[ci]), 0.f);
    acc = fmaf(wrow[ci], xv, acc);
  }
  dst[((size_t)(b * 512 + co) << 12) + n] = f2bf(acc);
}

// ---------------- K9: fusion + all three class heads, f32 outputs ------------
__global__ __launch_bounds__(256) void k_heads(const u16* __restrict__ sa2,
    const u16* __restrict__ sc2,
    const float* __restrict__ wf, const float* __restrict__ wa, const float* __restrict__ wc,
    const float* __restrict__ bfb, const float* __restrict__ bab, const float* __restrict__ bcb,
    float* __restrict__ outFusion, float* __restrict__ outCls) {
  int t = threadIdx.x;
  int b = blockIdx.y;
  int n = blockIdx.x * 256 + t;
  float af[5] = {}, aa[5] = {}, ac[5] = {};
  for (int c = 0; c < 512; ++c) {
    size_t o = ((size_t)(b * 512 + c) << 12) + n;
    float a = bf2f(sa2[o]), cc = bf2f(sc2[o]);
    float s = a + cc;
    outFusion[o] = s;
#pragma unroll
    for (int cls = 0; cls < 5; ++cls) {
      af[cls] = fmaf(wf[cls * 512 + c], s, af[cls]);
      aa[cls] = fmaf(wa[cls * 512 + c], a, aa[cls]);
      ac[cls] = fmaf(wc[cls * 512 + c], cc, ac[cls]);
    }
  }
#pragma unroll
  for (int cls = 0; cls < 5; ++cls) {
    int o = ((b * 5 + cls) << 12) + n;
    outCls[o] = af[cls] + bfb[cls];
    outCls[40960 + o] = aa[cls] + bab[cls];
    outCls[81920 + o] = ac[cls] + bcb[cls];
  }
}

extern "C" void kernel_launch(void* const* d_in, const int* in_sizes, int n_in,
                              void* d_out, int out_size, void* d_ws, size_t ws_size,
                              hipStream_t stream) {
  (void)in_sizes; (void)n_in; (void)out_size; (void)ws_size;
  const float* x      = (const float*)d_in[0];
  const float* bnaw   = (const float*)d_in[1];
  const float* bnab   = (const float*)d_in[2];
  const float* bnam   = (const float*)d_in[3];
  const float* bnav   = (const float*)d_in[4];
  const float* convaw = (const float*)d_in[5];
  const float* bncw   = (const float*)d_in[6];
  const float* bncb   = (const float*)d_in[7];
  const float* bncm   = (const float*)d_in[8];
  const float* bncv   = (const float*)d_in[9];
  const float* convcw = (const float*)d_in[10];
  const float* pqw    = (const float*)d_in[11];
  const float* pqb    = (const float*)d_in[12];
  const float* pkw    = (const float*)d_in[13];
  const float* pkb    = (const float*)d_in[14];
  const float* pvw    = (const float*)d_in[15];
  const float* pvb    = (const float*)d_in[16];
  const float* pgam   = (const float*)d_in[17];
  const float* cgam   = (const float*)d_in[18];
  const float* bna1w  = (const float*)d_in[19];
  const float* bna1b  = (const float*)d_in[20];
  const float* bna1m  = (const float*)d_in[21];
  const float* bna1v  = (const float*)d_in[22];
  const float* conva1w = (const float*)d_in[23];
  const float* conva1b = (const float*)d_in[24];
  const float* bnc1w  = (const float*)d_in[25];
  const float* bnc1b  = (const float*)d_in[26];
  const float* bnc1m  = (const float*)d_in[27];
  const float* bnc1v  = (const float*)d_in[28];
  const float* convc1w = (const float*)d_in[29];
  const float* convc1b = (const float*)d_in[30];
  const float* outaw  = (const float*)d_in[31];
  const float* outab  = (const float*)d_in[32];
  const float* outcw  = (const float*)d_in[33];
  const float* outcb  = (const float*)d_in[34];
  const float* outfw  = (const float*)d_in[35];
  const float* outfb  = (const float*)d_in[36];

  char* wsb = (char*)d_ws;
  size_t off = 0;
  auto take = [&](size_t bytes) -> void* {
    void* p = wsb + off;
    off += (bytes + 255) & ~(size_t)255;
    return p;
  };
  float* wvT   = (float*)take((size_t)128 * 128 * 4);
  float* xa    = (float*)take((size_t)2 * 512 * 4096 * 4);
  float* xcb   = (float*)take((size_t)2 * 512 * 4096 * 4);
  float* sa0   = (float*)take((size_t)2 * 128 * 4096 * 4);
  float* sc0   = (float*)take((size_t)2 * 128 * 4096 * 4);
  float* qb    = (float*)take((size_t)2 * 16 * 4096 * 4);
  float* kbuf  = (float*)take((size_t)2 * 16 * 4096 * 4);
  float* vt    = (float*)take((size_t)2 * 4096 * 128 * 4);
  float* rmax  = (float*)take((size_t)2 * 4096 * 4);
  float* rinv  = (float*)take((size_t)2 * 4096 * 4);
  float* sa1   = (float*)take((size_t)2 * 128 * 4096 * 4);
  float* sc1   = (float*)take((size_t)2 * 128 * 4096 * 4);
  float* energy = (float*)take((size_t)2 * 128 * 128 * 4);
  float* attn  = (float*)take((size_t)2 * 128 * 128 * 4);
  u16*   sa2   = (u16*)take((size_t)2 * 512 * 4096 * 2);
  u16*   sc2   = (u16*)take((size_t)2 * 512 * 4096 * 2);

  float* outF = (float*)d_out;
  float* outCls = outF + (size_t)2 * 512 * 4096;

  k_prep_wv<<<64, 256, 0, stream>>>(pvw, wvT);
  k_bnrelu2<<<4096, 256, 0, stream>>>(x, bnaw, bnab, bnam, bnav,
                                      bncw, bncb, bncm, bncv, xa, xcb);
  k_conv3t<<<dim3(16, 8, 4), 256, 0, stream>>>(xa, xcb, convaw, convcw, sa0, sc0);
  k_qk<<<dim3(16, 32, 2), 256, 0, stream>>>(sa0, pqw, pqb, pkw, pkb, qb, kbuf);
  k_vt<<<dim3(2048, 2), 256, 0, stream>>>(sa0, wvT, pvb, vt);
  k_pam_stats<<<dim3(1024, 2), 256, 0, stream>>>(qb, kbuf, rmax, rinv);
  k_pam_pv<<<dim3(4096, 2), 256, 0, stream>>>(qb, kbuf, vt, rmax, rinv, sa0, pgam, sa1);
  k_cam_energy<<<dim3(128, 2), 256, 0, stream>>>(sc0, energy);
  k_cam_softmax<<<dim3(128, 2), 64, 0, stream>>>(energy, attn);
  k_cam_out<<<dim3(16, 8, 2), 256, 0, stream>>>(sc0, attn, cgam, sc1);
  k_branch_out<<<dim3(16, 512, 4), 256, 0, stream>>>(sa1, sc1,
      bna1w, bna1b, bna1m, bna1v, bnc1w, bnc1b, bnc1m, bnc1v,
      conva1w, conva1b, convc1w, convc1b, sa2, sc2);
  k_heads<<<dim3(16, 2), 256, 0, stream>>>(sa2, sc2, outfw, outaw, outcw,
                                           outfb, outab, outcb, outF, outCls);
}

// Round 7
// 1445.216 us; speedup vs baseline: 2.0573x; 1.4685x over previous
//
#include <hip/hip_runtime.h>

using u16 = unsigned short;

__device__ __forceinline__ float bf2f(u16 u) {
  return __uint_as_float(((unsigned int)u) << 16);
}
__device__ __forceinline__ u16 f2bf(float f) {
  unsigned int u = __float_as_uint(f);
  unsigned int r = u + 0x7FFFu + ((u >> 16) & 1u);
  return (u16)(r >> 16);
}

// ---------------- K0: transpose pam_v_w [c][ci] -> wvT [ci][c] ---------------
__global__ void k_prep_wv(const float* __restrict__ wv, float* __restrict__ wvT) {
  int idx = blockIdx.x * 256 + threadIdx.x;   // 16384
  int ci = idx >> 7, c = idx & 127;
  wvT[ci * 128 + c] = wv[c * 128 + ci];
}

// ---------------- K1: BN+ReLU for both branches, f32 out ---------------------
__global__ void k_bnrelu2(const float* __restrict__ x,
    const float* __restrict__ wa, const float* __restrict__ ba,
    const float* __restrict__ ma, const float* __restrict__ va,
    const float* __restrict__ wc, const float* __restrict__ bc,
    const float* __restrict__ mc, const float* __restrict__ vc,
    float* __restrict__ xa, float* __restrict__ xcb) {
  int i4 = (blockIdx.x * 256 + threadIdx.x) * 4;   // over 2*512*4096
  int c = (i4 >> 12) & 511;
  float sA = wa[c] * rsqrtf(va[c] + 1e-5f);
  float bA = ba[c] - ma[c] * sA;
  float sC = wc[c] * rsqrtf(vc[c] + 1e-5f);
  float bC = bc[c] - mc[c] * sC;
  float4 xv = *(const float4*)(x + i4);
  float4 oa, oc;
  oa.x = fmaxf(xv.x * sA + bA, 0.f); oc.x = fmaxf(xv.x * sC + bC, 0.f);
  oa.y = fmaxf(xv.y * sA + bA, 0.f); oc.y = fmaxf(xv.y * sC + bC, 0.f);
  oa.z = fmaxf(xv.z * sA + bA, 0.f); oc.z = fmaxf(xv.z * sC + bC, 0.f);
  oa.w = fmaxf(xv.w * sA + bA, 0.f); oc.w = fmaxf(xv.w * sC + bC, 0.f);
  *(float4*)(xa + i4) = oa;
  *(float4*)(xcb + i4) = oc;
}

// ---------------- K2: 3x3 conv SAME 512->128, co-tile 8, 1024 blocks ---------
// block: 256 thr = 4 rows x 64 cols; computes 8 co for that tile.
// grid: (16 h-groups, 16 co-groups, 4: z = b + 2*branch)
__global__ __launch_bounds__(256) void k_conv3t(
    const float* __restrict__ xa, const float* __restrict__ xcb,
    const float* __restrict__ wa, const float* __restrict__ wc,
    float* __restrict__ sa0, float* __restrict__ sc0) {
  __shared__ float ls[16 * 396];   // 16 ci x 6 rows x 66 (w-halo), zero-padded
  int t = threadIdx.x;
  int hg = blockIdx.x, cg = blockIdx.y, z = blockIdx.z;
  int b = z & 1, br = z >> 1;
  const float* xin = br ? xcb : xa;
  const float* wconv = br ? wc : wa;
  float* out = br ? sc0 : sa0;
  int h0 = hg * 4;
  int w = t & 63, hl = t >> 6;
  int co0 = cg * 8;
  float acc[8] = {};
  const float* xb = xin + ((size_t)b * 512 << 12);
  for (int ci0 = 0; ci0 < 512; ci0 += 16) {
    __syncthreads();
    for (int idx = t; idx < 6336; idx += 256) {
      int ci_l = idx / 396;
      int rem = idx - ci_l * 396;
      int row = rem / 66;
      int w66 = rem - row * 66;
      int gh = h0 - 1 + row;
      int gw = w66 - 1;
      float v = 0.f;
      if (gh >= 0 && gh < 64 && gw >= 0 && gw < 64)
        v = xb[((size_t)(ci0 + ci_l) << 12) + (gh << 6) + gw];
      ls[idx] = v;
    }
    __syncthreads();
    for (int ci_l = 0; ci_l < 16; ++ci_l) {
      const float* c = ls + ci_l * 396 + (hl + 1) * 66 + (w + 1);
      float x00 = c[-67], x01 = c[-66], x02 = c[-65];
      float x10 = c[-1],  x11 = c[0],   x12 = c[1];
      float x20 = c[65],  x21 = c[66],  x22 = c[67];
      const float* wp = wconv + (size_t)co0 * 4608 + (ci0 + ci_l) * 9;
#pragma unroll
      for (int co = 0; co < 8; ++co) {
        const float* wq = wp + co * 4608;   // block-uniform -> scalar loads
        acc[co] = fmaf(wq[0], x00, fmaf(wq[1], x01, fmaf(wq[2], x02,
                  fmaf(wq[3], x10, fmaf(wq[4], x11, fmaf(wq[5], x12,
                  fmaf(wq[6], x20, fmaf(wq[7], x21, fmaf(wq[8], x22, acc[co])))))))));
      }
    }
  }
  int hw = ((h0 + hl) << 6) + w;
#pragma unroll
  for (int co = 0; co < 8; ++co)
    out[((size_t)(b * 128 + co0 + co) << 12) + hw] = acc[co];
}

// ---------------- K3a: 1x1 conv -> q,k ([b][16][4096] f32) -------------------
__global__ void k_qk(const float* __restrict__ sa0,
    const float* __restrict__ wq, const float* __restrict__ bq,
    const float* __restrict__ wk, const float* __restrict__ bk,
    float* __restrict__ qb, float* __restrict__ kb) {
  int n = blockIdx.x * 256 + threadIdx.x;
  int co = blockIdx.y, b = blockIdx.z;
  const float* w; float* dst; float bias;
  if (co < 16) { w = wq + co * 128; bias = bq[co]; dst = qb + ((b * 16 + co) << 12); }
  else { int c2 = co - 16; w = wk + c2 * 128; bias = bk[c2]; dst = kb + ((b * 16 + c2) << 12); }
  const float* s = sa0 + ((size_t)b * 128 << 12) + n;
  float acc = bias;
  for (int ci = 0; ci < 128; ++ci) acc = fmaf(w[ci], s[ci << 12], acc);
  dst[n] = acc;
}

// ---------------- K3b: 1x1 conv -> v, stored transposed vt[b][n][c] ----------
__global__ void k_vt(const float* __restrict__ sa0, const float* __restrict__ wvT,
                     const float* __restrict__ bv, float* __restrict__ vt) {
  int t = threadIdx.x;
  int c = t & 127, nh = t >> 7;
  int n = blockIdx.x * 2 + nh, b = blockIdx.y;
  const float* s = sa0 + ((size_t)b * 128 << 12) + n;
  float acc = bv[c];
  for (int ci = 0; ci < 128; ++ci) acc = fmaf(wvT[ci * 128 + c], s[ci << 12], acc);
  vt[((size_t)(b * 4096 + n)) * 128 + c] = acc;
}

// ---------------- K4: PAM softmax row stats (max, 1/sum) ---------------------
__global__ __launch_bounds__(256) void k_pam_stats(const float* __restrict__ qb,
    const float* __restrict__ kb, float* __restrict__ rmax, float* __restrict__ rinv) {
  int t = threadIdx.x, lane = t & 63, wid = t >> 6;
  int b = blockIdx.y;
  int n = blockIdx.x * 4 + wid;
  float qreg[16];
  const float* qp = qb + ((size_t)b * 16 << 12) + n;
#pragma unroll
  for (int ch = 0; ch < 16; ++ch) qreg[ch] = qp[ch << 12];
  const float* kp = kb + ((size_t)b * 16 << 12);
  float mx = -1e30f, se = 0.f;
  for (int m = lane; m < 4096; m += 64) {
    float e = 0.f;
#pragma unroll
    for (int ch = 0; ch < 16; ++ch) e = fmaf(qreg[ch], kp[(ch << 12) + m], e);
    float nm = fmaxf(mx, e);
    se = se * __expf(mx - nm) + __expf(e - nm);
    mx = nm;
  }
#pragma unroll
  for (int off = 32; off >= 1; off >>= 1) {
    float om = __shfl_xor(mx, off);
    float os = __shfl_xor(se, off);
    float nm = fmaxf(mx, om);
    se = se * __expf(mx - nm) + os * __expf(om - nm);
    mx = nm;
  }
  if (lane == 0) { rmax[(b << 12) + n] = mx; rinv[(b << 12) + n] = 1.f / se; }
}

// ---------------- K5: PAM PV, 32-n tile per block (vt streamed once/tile) ----
__global__ __launch_bounds__(256) void k_pam_pv(const float* __restrict__ qb,
    const float* __restrict__ kb, const float* __restrict__ vt,
    const float* __restrict__ rmax, const float* __restrict__ rinv,
    const float* __restrict__ sa0, const float* __restrict__ gamma,
    float* __restrict__ sa1) {
  __shared__ float qs[512];        // [ch][32 n]
  __shared__ float ks[1024];       // [ch][64 m]
  __shared__ float pbs[2048];      // [64 m][32 n]
  __shared__ float mxs[32], invs[32];
  __shared__ float obuf[128 * 33];
  int t = threadIdx.x;
  int b = blockIdx.y, n0 = blockIdx.x * 32;
  for (int idx = t; idx < 512; idx += 256) {
    int ch = idx >> 5, r = idx & 31;
    qs[idx] = qb[((b * 16 + ch) << 12) + n0 + r];
  }
  if (t < 32) { mxs[t] = rmax[(b << 12) + n0 + t]; invs[t] = rinv[(b << 12) + n0 + t]; }
  int cp = t & 63, qd = t >> 6;
  float acc[8][2] = {};
  const float* kpb = kb + ((size_t)b * 16 << 12);
  for (int m0 = 0; m0 < 4096; m0 += 64) {
    for (int idx = t; idx < 1024; idx += 256) {
      int ch = idx >> 6, mm = idx & 63;
      ks[idx] = kpb[(ch << 12) + m0 + mm];
    }
    __syncthreads();
#pragma unroll
    for (int g = 0; g < 2; ++g) {
      int idx = t + 256 * g;
      int m = idx >> 3, r0 = (idx & 7) * 4;
      float e0 = 0.f, e1 = 0.f, e2 = 0.f, e3 = 0.f;
#pragma unroll
      for (int ch = 0; ch < 16; ++ch) {
        float kk = ks[(ch << 6) + m];
        float4 qv = *(const float4*)(qs + (ch << 5) + r0);
        e0 = fmaf(kk, qv.x, e0); e1 = fmaf(kk, qv.y, e1);
        e2 = fmaf(kk, qv.z, e2); e3 = fmaf(kk, qv.w, e3);
      }
      float4 mv = *(const float4*)(mxs + r0);
      float4 iv = *(const float4*)(invs + r0);
      float4 pv;
      pv.x = __expf(fminf(e0 - mv.x, 0.f)) * iv.x;
      pv.y = __expf(fminf(e1 - mv.y, 0.f)) * iv.y;
      pv.z = __expf(fminf(e2 - mv.z, 0.f)) * iv.z;
      pv.w = __expf(fminf(e3 - mv.w, 0.f)) * iv.w;
      *(float4*)(pbs + (m << 5) + r0) = pv;
    }
    __syncthreads();
    const float* vp = vt + ((size_t)(b * 4096 + m0)) * 128 + (cp << 1);
#pragma unroll 4
    for (int mm = 0; mm < 64; ++mm) {
      float2 vv = *(const float2*)(vp + mm * 128);
      const float* pp = pbs + (mm << 5) + (qd << 3);
      float4 pA = *(const float4*)pp;
      float4 pB = *(const float4*)(pp + 4);
      acc[0][0] = fmaf(pA.x, vv.x, acc[0][0]); acc[0][1] = fmaf(pA.x, vv.y, acc[0][1]);
      acc[1][0] = fmaf(pA.y, vv.x, acc[1][0]); acc[1][1] = fmaf(pA.y, vv.y, acc[1][1]);
      acc[2][0] = fmaf(pA.z, vv.x, acc[2][0]); acc[2][1] = fmaf(pA.z, vv.y, acc[2][1]);
      acc[3][0] = fmaf(pA.w, vv.x, acc[3][0]); acc[3][1] = fmaf(pA.w, vv.y, acc[3][1]);
      acc[4][0] = fmaf(pB.x, vv.x, acc[4][0]); acc[4][1] = fmaf(pB.x, vv.y, acc[4][1]);
      acc[5][0] = fmaf(pB.y, vv.x, acc[5][0]); acc[5][1] = fmaf(pB.y, vv.y, acc[5][1]);
      acc[6][0] = fmaf(pB.z, vv.x, acc[6][0]); acc[6][1] = fmaf(pB.z, vv.y, acc[6][1]);
      acc[7][0] = fmaf(pB.w, vv.x, acc[7][0]); acc[7][1] = fmaf(pB.w, vv.y, acc[7][1]);
    }
    __syncthreads();
  }
  // transpose through LDS for coalesced-in-n stores
#pragma unroll
  for (int r = 0; r < 8; ++r) {
    obuf[(2 * cp + 0) * 33 + (qd << 3) + r] = acc[r][0];
    obuf[(2 * cp + 1) * 33 + (qd << 3) + r] = acc[r][1];
  }
  __syncthreads();
  float g = gamma[0];
  for (int idx = t; idx < 4096; idx += 256) {
    int c = idx >> 5, nn = idx & 31;
    size_t o = ((size_t)(b * 128 + c) << 12) + n0 + nn;
    sa1[o] = fmaf(g, obuf[c * 33 + nn], sa0[o]);
  }
}

// ---------------- K6a: CAM Gram energy, block per row c, deterministic -------
__global__ __launch_bounds__(256) void k_cam_energy(const float* __restrict__ f,
                                                    float* __restrict__ energy) {
  __shared__ float fc[4096];
  int t = threadIdx.x;
  int c = blockIdx.x, b = blockIdx.y;
  const float* fr = f + ((size_t)(b * 128 + c) << 12);
  for (int i = t; i < 4096; i += 256) fc[i] = fr[i];
  __syncthreads();
  if (t < 128) {
    int d = t;
    const float* fd = f + ((size_t)(b * 128 + d) << 12);
    float acc = 0.f;
    for (int nn = 0; nn < 4096; ++nn) acc = fmaf(fc[nn], fd[nn], acc);
    energy[((b * 128 + c) << 7) + d] = acc;
  }
}

// ---------------- K6b: CAM softmax row (attn = softmax(rowmax - e)) ----------
__global__ void k_cam_softmax(const float* __restrict__ energy, float* __restrict__ attn) {
  int lane = threadIdx.x;   // 64
  int c = blockIdx.x, b = blockIdx.y;
  const float* e = energy + ((b * 128 + c) << 7);
  float e0 = e[lane], e1 = e[lane + 64];
  float mn = fminf(e0, e1);
#pragma unroll
  for (int off = 32; off >= 1; off >>= 1) mn = fminf(mn, __shfl_xor(mn, off));
  float p0 = __expf(fminf(mn - e0, 0.f)), p1 = __expf(fminf(mn - e1, 0.f));
  float s = p0 + p1;
#pragma unroll
  for (int off = 32; off >= 1; off >>= 1) s += __shfl_xor(s, off);
  float inv = 1.f / s;
  float* a = attn + ((b * 128 + c) << 7);
  a[lane] = p0 * inv;
  a[lane + 64] = p1 * inv;
}

// ---------------- K7: CAM out + residual -------------------------------------
__global__ __launch_bounds__(256) void k_cam_out(const float* __restrict__ f,
    const float* __restrict__ attn, const float* __restrict__ gamma,
    float* __restrict__ sc1) {
  __shared__ float at2[128 * 16];
  int t = threadIdx.x;
  int b = blockIdx.z, c0 = blockIdx.y * 16;
  int n = blockIdx.x * 256 + t;
  for (int idx = t; idx < 2048; idx += 256) {
    int d = idx >> 4, cc = idx & 15;
    at2[idx] = attn[((b * 128 + c0 + cc) << 7) + d];
  }
  __syncthreads();
  float acc[16] = {};
  const float* fb = f + ((size_t)b * 128 << 12) + n;
  for (int d = 0; d < 128; ++d) {
    float fv = fb[d << 12];
    const float* ap = at2 + d * 16;
#pragma unroll
    for (int cc = 0; cc < 16; ++cc) acc[cc] = fmaf(ap[cc], fv, acc[cc]);
  }
  float g = gamma[0];
#pragma unroll
  for (int cc = 0; cc < 16; ++cc) {
    size_t o = ((size_t)(b * 128 + c0 + cc) << 12) + n;
    sc1[o] = fmaf(g, acc[cc], f[o]);
  }
}

// ---------------- K8: BN+ReLU + 1x1 conv 128->512, 16 co per block -----------
__global__ __launch_bounds__(256) void k_branch_out(
    const float* __restrict__ sa1, const float* __restrict__ sc1,
    const float* __restrict__ wa_, const float* __restrict__ ba_,
    const float* __restrict__ ma_, const float* __restrict__ va_,
    const float* __restrict__ wc_, const float* __restrict__ bc_,
    const float* __restrict__ mc_, const float* __restrict__ vc_,
    const float* __restrict__ Wa, const float* __restrict__ Ba,
    const float* __restrict__ Wc, const float* __restrict__ Bc,
    u16* __restrict__ sa2, u16* __restrict__ sc2) {
  int z = blockIdx.z;
  int b = z & 1, br = z >> 1;
  const float* src = br ? sc1 : sa1;
  const float* bw = br ? wc_ : wa_;
  const float* bb = br ? bc_ : ba_;
  const float* bm = br ? mc_ : ma_;
  const float* bvv = br ? vc_ : va_;
  const float* W = br ? Wc : Wa;
  const float* Bs = br ? Bc : Ba;
  u16* dst = br ? sc2 : sa2;
  __shared__ float wl[128 * 16];
  __shared__ float scl[128], shf[128];
  int t = threadIdx.x;
  int co0 = blockIdx.y * 16;
  int n = blockIdx.x * 256 + t;
  if (t < 128) {
    float s = bw[t] * rsqrtf(bvv[t] + 1e-5f);
    scl[t] = s;
    shf[t] = bb[t] - bm[t] * s;
  }
  for (int idx = t; idx < 2048; idx += 256) {
    int ci = idx >> 4, cc = idx & 15;
    wl[idx] = W[(co0 + cc) * 128 + ci];
  }
  __syncthreads();
  float acc[16] = {};
  const float* sp = src + ((size_t)b * 128 << 12) + n;
  for (int ci = 0; ci < 128; ++ci) {
    float xv = fmaxf(fmaf(sp[ci << 12], scl[ci], shf[ci]), 0.f);
    const float* wp = wl + ci * 16;
    float4 w0 = *(const float4*)wp;
    float4 w1 = *(const float4*)(wp + 4);
    float4 w2 = *(const float4*)(wp + 8);
    float4 w3 = *(const float4*)(wp + 12);
    acc[0] = fmaf(w0.x, xv, acc[0]);  acc[1] = fmaf(w0.y, xv, acc[1]);
    acc[2] = fmaf(w0.z, xv, acc[2]);  acc[3] = fmaf(w0.w, xv, acc[3]);
    acc[4] = fmaf(w1.x, xv, acc[4]);  acc[5] = fmaf(w1.y, xv, acc[5]);
    acc[6] = fmaf(w1.z, xv, acc[6]);  acc[7] = fmaf(w1.w, xv, acc[7]);
    acc[8] = fmaf(w2.x, xv, acc[8]);  acc[9] = fmaf(w2.y, xv, acc[9]);
    acc[10] = fmaf(w2.z, xv, acc[10]); acc[11] = fmaf(w2.w, xv, acc[11]);
    acc[12] = fmaf(w3.x, xv, acc[12]); acc[13] = fmaf(w3.y, xv, acc[13]);
    acc[14] = fmaf(w3.z, xv, acc[14]); acc[15] = fmaf(w3.w, xv, acc[15]);
  }
#pragma unroll
  for (int cc = 0; cc < 16; ++cc) {
    dst[((size_t)(b * 512 + co0 + cc) << 12) + n] = f2bf(acc[cc] + Bs[co0 + cc]);
  }
}

// ---------------- K9: fusion + all three class heads, f32 outputs ------------
__global__ __launch_bounds__(256) void k_heads(const u16* __restrict__ sa2,
    const u16* __restrict__ sc2,
    const float* __restrict__ wf, const float* __restrict__ wa, const float* __restrict__ wc,
    const float* __restrict__ bfb, const float* __restrict__ bab, const float* __restrict__ bcb,
    float* __restrict__ outFusion, float* __restrict__ outCls) {
  int t = threadIdx.x;
  int b = blockIdx.y;
  int n = blockIdx.x * 256 + t;
  float af[5] = {}, aa[5] = {}, ac[5] = {};
  for (int c = 0; c < 512; ++c) {
    size_t o = ((size_t)(b * 512 + c) << 12) + n;
    float a = bf2f(sa2[o]), cc = bf2f(sc2[o]);
    float s = a + cc;
    outFusion[o] = s;
#pragma unroll
    for (int cls = 0; cls < 5; ++cls) {
      af[cls] = fmaf(wf[cls * 512 + c], s, af[cls]);
      aa[cls] = fmaf(wa[cls * 512 + c], a, aa[cls]);
      ac[cls] = fmaf(wc[cls * 512 + c], cc, ac[cls]);
    }
  }
#pragma unroll
  for (int cls = 0; cls < 5; ++cls) {
    int o = ((b * 5 + cls) << 12) + n;
    outCls[o] = af[cls] + bfb[cls];
    outCls[40960 + o] = aa[cls] + bab[cls];
    outCls[81920 + o] = ac[cls] + bcb[cls];
  }
}

extern "C" void kernel_launch(void* const* d_in, const int* in_sizes, int n_in,
                              void* d_out, int out_size, void* d_ws, size_t ws_size,
                              hipStream_t stream) {
  (void)in_sizes; (void)n_in; (void)out_size; (void)ws_size;
  const float* x      = (const float*)d_in[0];
  const float* bnaw   = (const float*)d_in[1];
  const float* bnab   = (const float*)d_in[2];
  const float* bnam   = (const float*)d_in[3];
  const float* bnav   = (const float*)d_in[4];
  const float* convaw = (const float*)d_in[5];
  const float* bncw   = (const float*)d_in[6];
  const float* bncb   = (const float*)d_in[7];
  const float* bncm   = (const float*)d_in[8];
  const float* bncv   = (const float*)d_in[9];
  const float* convcw = (const float*)d_in[10];
  const float* pqw    = (const float*)d_in[11];
  const float* pqb    = (const float*)d_in[12];
  const float* pkw    = (const float*)d_in[13];
  const float* pkb    = (const float*)d_in[14];
  const float* pvw    = (const float*)d_in[15];
  const float* pvb    = (const float*)d_in[16];
  const float* pgam   = (const float*)d_in[17];
  const float* cgam   = (const float*)d_in[18];
  const float* bna1w  = (const float*)d_in[19];
  const float* bna1b  = (const float*)d_in[20];
  const float* bna1m  = (const float*)d_in[21];
  const float* bna1v  = (const float*)d_in[22];
  const float* conva1w = (const float*)d_in[23];
  const float* conva1b = (const float*)d_in[24];
  const float* bnc1w  = (const float*)d_in[25];
  const float* bnc1b  = (const float*)d_in[26];
  const float* bnc1m  = (const float*)d_in[27];
  const float* bnc1v  = (const float*)d_in[28];
  const float* convc1w = (const float*)d_in[29];
  const float* convc1b = (const float*)d_in[30];
  const float* outaw  = (const float*)d_in[31];
  const float* outab  = (const float*)d_in[32];
  const float* outcw  = (const float*)d_in[33];
  const float* outcb  = (const float*)d_in[34];
  const float* outfw  = (const float*)d_in[35];
  const float* outfb  = (const float*)d_in[36];

  char* wsb = (char*)d_ws;
  size_t off = 0;
  auto take = [&](size_t bytes) -> void* {
    void* p = wsb + off;
    off += (bytes + 255) & ~(size_t)255;
    return p;
  };
  float* wvT   = (float*)take((size_t)128 * 128 * 4);
  float* xa    = (float*)take((size_t)2 * 512 * 4096 * 4);
  float* xcb   = (float*)take((size_t)2 * 512 * 4096 * 4);
  float* sa0   = (float*)take((size_t)2 * 128 * 4096 * 4);
  float* sc0   = (float*)take((size_t)2 * 128 * 4096 * 4);
  float* qb    = (float*)take((size_t)2 * 16 * 4096 * 4);
  float* kbuf  = (float*)take((size_t)2 * 16 * 4096 * 4);
  float* vt    = (float*)take((size_t)2 * 4096 * 128 * 4);
  float* rmax  = (float*)take((size_t)2 * 4096 * 4);
  float* rinv  = (float*)take((size_t)2 * 4096 * 4);
  float* sa1   = (float*)take((size_t)2 * 128 * 4096 * 4);
  float* sc1   = (float*)take((size_t)2 * 128 * 4096 * 4);
  float* energy = (float*)take((size_t)2 * 128 * 128 * 4);
  float* attn  = (float*)take((size_t)2 * 128 * 128 * 4);
  u16*   sa2   = (u16*)take((size_t)2 * 512 * 4096 * 2);
  u16*   sc2   = (u16*)take((size_t)2 * 512 * 4096 * 2);

  float* outF = (float*)d_out;
  float* outCls = outF + (size_t)2 * 512 * 4096;

  k_prep_wv<<<64, 256, 0, stream>>>(pvw, wvT);
  k_bnrelu2<<<4096, 256, 0, stream>>>(x, bnaw, bnab, bnam, bnav,
                                      bncw, bncb, bncm, bncv, xa, xcb);
  k_conv3t<<<dim3(16, 16, 4), 256, 0, stream>>>(xa, xcb, convaw, convcw, sa0, sc0);
  k_qk<<<dim3(16, 32, 2), 256, 0, stream>>>(sa0, pqw, pqb, pkw, pkb, qb, kbuf);
  k_vt<<<dim3(2048, 2), 256, 0, stream>>>(sa0, wvT, pvb, vt);
  k_pam_stats<<<dim3(1024, 2), 256, 0, stream>>>(qb, kbuf, rmax, rinv);
  k_pam_pv<<<dim3(128, 2), 256, 0, stream>>>(qb, kbuf, vt, rmax, rinv, sa0, pgam, sa1);
  k_cam_energy<<<dim3(128, 2), 256, 0, stream>>>(sc0, energy);
  k_cam_softmax<<<dim3(128, 2), 64, 0, stream>>>(energy, attn);
  k_cam_out<<<dim3(16, 8, 2), 256, 0, stream>>>(sc0, attn, cgam, sc1);
  k_branch_out<<<dim3(16, 32, 4), 256, 0, stream>>>(sa1, sc1,
      bna1w, bna1b, bna1m, bna1v, bnc1w, bnc1b, bnc1m, bnc1v,
      conva1w, conva1b, convc1w, convc1b, sa2, sc2);
  k_heads<<<dim3(16, 2), 256, 0, stream>>>(sa2, sc2, outfw, outaw, outcw,
                                           outfb, outab, outcb, outF, outCls);
}